// Round 3
// baseline (2526.100 us; speedup 1.0000x reference)
//
#include <hip/hip_runtime.h>

typedef unsigned short u16;
typedef unsigned int u32;

#define NNODES 20000
#define NEDGES 640000
// GAMMA = 1/(2*(sqrt(2)/15)^2) = 56.25 exactly
#define RBF_GAMMA 56.25f
#define SQRT2 1.4142135623730951f

typedef __bf16 bf16x8 __attribute__((ext_vector_type(8)));
typedef float f32x4 __attribute__((ext_vector_type(4)));

__device__ __forceinline__ float b2f(u16 u) {
    union { float f; u32 i; } x; x.i = ((u32)u) << 16; return x.f;
}
__device__ __forceinline__ u16 f2b(float f) {
    union { float f; u32 i; } x; x.f = f;
    u32 r = (x.i + 0x7fffu + ((x.i >> 16) & 1u)) >> 16;
    return (u16)r;
}
__device__ __forceinline__ float silu(float v) {
    return v / (1.0f + __expf(-v));
}

// ---------------- sort by dst (counting sort) ----------------
__global__ __launch_bounds__(256) void k_hist(const int* __restrict__ ei, int* __restrict__ hist) {
    int e = blockIdx.x * 256 + threadIdx.x;
    atomicAdd(&hist[ei[NEDGES + e]], 1);
}

__global__ __launch_bounds__(1024) void k_scan(const int* __restrict__ hist,
                                               int* __restrict__ row_ptr,
                                               int* __restrict__ cursor) {
    __shared__ int psum[1024];
    int t = threadIdx.x;
    int base = t * 20;
    int s = 0;
    if (base < NNODES)
        for (int i = 0; i < 20; ++i) s += hist[base + i];
    psum[t] = s;
    __syncthreads();
    for (int off = 1; off < 1024; off <<= 1) {
        int v = (t >= off) ? psum[t - off] : 0;
        __syncthreads();
        psum[t] += v;
        __syncthreads();
    }
    int excl = psum[t] - s;
    if (base < NNODES) {
        int run = excl;
        for (int i = 0; i < 20; ++i) {
            row_ptr[base + i] = run;
            cursor[base + i] = run;
            run += hist[base + i];
        }
    }
    if (t == 1023) row_ptr[NNODES] = psum[1023];
}

__global__ __launch_bounds__(256) void k_scatter(const int* __restrict__ ei, int* __restrict__ cursor,
                                                 int* __restrict__ ssrc, int* __restrict__ sdst) {
    int e = blockIdx.x * 256 + threadIdx.x;
    int d = ei[NEDGES + e];
    int pos = atomicAdd(&cursor[d], 1);
    ssrc[pos] = ei[e];
    sdst[pos] = d;
}

// ---------------- W1 (fp32) -> bf16 frag-order shuffle ----------------
// layout: [l][kc(9)][nt(8)][lane(64)][8]  ; value = W1[kc*32+(lane>>4)*8+j][nt*16+(lane&15)]
__global__ __launch_bounds__(256) void k_prep_w1s(const float* __restrict__ pmw1, u16* __restrict__ W1s) {
    int id = blockIdx.x * 256 + threadIdx.x;   // 13824 total
    int l = id / 4608; int r = id - l * 4608;
    int kc = r / 512;  int r2 = r - kc * 512;
    int nt = r2 >> 6;  int lane = r2 & 63;
    int kb = kc * 32 + (lane >> 4) * 8;
    int n = nt * 16 + (lane & 15);
    #pragma unroll
    for (int jj = 0; jj < 8; ++jj) {
        int k = kb + jj;
        W1s[id * 8 + jj] = (k < 272) ? f2b(pmw1[l * 34816 + k * 128 + n]) : (u16)0;
    }
}

// ---------------- transpose fp32 [K][128] -> fp32 [128][K] ----------------
struct TMats { const float* s[8]; float* d[8]; };
__global__ __launch_bounds__(256) void k_transpose128(TMats tm) {
    int m = blockIdx.y;
    int idx = blockIdx.x * 256 + threadIdx.x;  // < 16384
    int k = idx >> 7, j = idx & 127;
    tm.d[m][j * 128 + k] = tm.s[m][k * 128 + j];
}
__global__ __launch_bounds__(256) void k_transpose_v1(const float* __restrict__ src, float* __restrict__ dst) {
    int l = blockIdx.y;
    int idx = blockIdx.x * 256 + threadIdx.x;  // < 32768
    int k = idx >> 7, j = idx & 127;
    dst[l * 32768 + j * 256 + k] = src[l * 32768 + k * 128 + j];
}

// ---------------- time embedding -> te -> base1 ----------------
__global__ __launch_bounds__(128) void k_time(const int* __restrict__ tptr,
        const float* __restrict__ tw1, const float* __restrict__ tb1,
        const float* __restrict__ tw2, const float* __restrict__ tb2,
        const float* __restrict__ nw1, const float* __restrict__ nb1,
        float* __restrict__ base1) {
    __shared__ float emb[128], hid[128], te[128];
    int j = threadIdx.x;
    int raw = tptr[0];
    float tv;
    if (raw >= 0 && raw < (1 << 24)) tv = (float)raw;   // int32-stored scalar (t=25)
    else tv = __int_as_float(raw);                       // fp32-stored fallback
    float fr = expf(-9.210340371976184f * (float)(j & 63) / 63.0f);
    float a = tv * fr;
    emb[j] = (j < 64) ? sinf(a) : cosf(a);
    __syncthreads();
    float acc = tb1[j];
    for (int k = 0; k < 128; ++k) acc += emb[k] * tw1[k * 128 + j];
    hid[j] = silu(acc);
    __syncthreads();
    acc = tb2[j];
    for (int k = 0; k < 128; ++k) acc += hid[k] * tw2[k * 128 + j];
    te[j] = acc;
    __syncthreads();
    acc = nb1[j];
    for (int k = 0; k < 128; ++k) acc += te[k] * nw1[(3 + k) * 128 + j];
    base1[j] = acc;
}

// ---------------- input node MLP ----------------
__global__ __launch_bounds__(256) void k_h0(const float* __restrict__ x, const float* __restrict__ base1,
        const float* __restrict__ nw1, const float* __restrict__ nw2t, const float* __restrict__ nb2,
        float* __restrict__ hf, u16* __restrict__ hb) {
    int j = threadIdx.x & 127, p = threadIdx.x >> 7;
    __shared__ alignas(16) float hid[2][128];
    __shared__ float xl[2][4];
    for (int it = 0; it < 4; ++it) {
        int n = blockIdx.x * 8 + it * 2 + p;
        if (j < 3) xl[p][j] = x[(size_t)n * 3 + j];
        __syncthreads();
        float acc = base1[j];
        #pragma unroll
        for (int k = 0; k < 3; ++k) acc += xl[p][k] * nw1[k * 128 + j];
        hid[p][j] = silu(acc);
        __syncthreads();
        float o = nb2[j];
        const float4* wr = (const float4*)(nw2t + j * 128);
        const float4* hp = (const float4*)hid[p];
        #pragma unroll 8
        for (int kk = 0; kk < 32; ++kk) {
            float4 w = wr[kk], h4 = hp[kk];
            o += w.x * h4.x + w.y * h4.y + w.z * h4.z + w.w * h4.w;
        }
        hf[(size_t)n * 128 + j] = o;
        hb[(size_t)n * 128 + j] = f2b(o);
        __syncthreads();
    }
}

// ---------------- edge message GEMM + silu + segment reduce ----------------
// A-tile: 64 sorted edges x 296 bf16 (h_src|h_dst|rbf|pad), MFMA 16x16x32 bf16
// dynamic LDS = 64*296*2 = 37888 B (reused as ss[64][132] f32 = 33792 B)
__global__ __launch_bounds__(256) void k_edge(
        const u16* __restrict__ hb, const float* __restrict__ x,
        const int* __restrict__ ssrc, const int* __restrict__ sdst,
        const u16* __restrict__ W1s, const float* __restrict__ b1,
        float* __restrict__ s_glob) {
    extern __shared__ char dynsm[];
    u16* sa = (u16*)dynsm;          // [64][296] bf16
    float* ss = (float*)dynsm;      // reused: [64][132] f32
    __shared__ int s_src[64], s_dst[64];
    const int tid = threadIdx.x;
    const int e0 = blockIdx.x * 64;
    if (tid < 64) { s_src[tid] = ssrc[e0 + tid]; s_dst[tid] = sdst[e0 + tid]; }
    __syncthreads();
    // stage h parts: 2048 chunks of 16B
    #pragma unroll
    for (int c = tid; c < 2048; c += 256) {
        int e = c >> 5, part = c & 31;
        int node = (part < 16) ? s_src[e] : s_dst[e];
        uint4 v = *(const uint4*)(hb + (size_t)node * 128 + (part & 15) * 8);
        *(uint4*)(sa + e * 296 + part * 8) = v;
    }
    // rbf (computed inline, fp32 coords) + zero pad: 5 chunks of 8 per edge
    for (int c = tid; c < 320; c += 256) {
        int e = c / 5, p = c - e * 5;
        if (p < 2) {
            int s = s_src[e], d = s_dst[e];
            float ddx = x[(size_t)s * 3] - x[(size_t)d * 3];
            float ddy = x[(size_t)s * 3 + 1] - x[(size_t)d * 3 + 1];
            float r = sqrtf(ddx * ddx + ddy * ddy + 1e-8f);
            alignas(16) u16 tmp[8];
            #pragma unroll
            for (int jj = 0; jj < 8; ++jj) {
                int j = p * 8 + jj;
                float cen = SQRT2 * (float)j / 15.0f;
                float dd = r - cen;
                tmp[jj] = f2b(__expf(-RBF_GAMMA * dd * dd));
            }
            *(uint4*)(sa + e * 296 + 256 + p * 8) = *(const uint4*)tmp;
        } else {
            *(uint4*)(sa + e * 296 + 256 + p * 8) = make_uint4(0, 0, 0, 0);
        }
    }
    __syncthreads();

    const int lane = tid & 63, w = tid >> 6;
    const int mh = w >> 1, nh = w & 1;      // mh: 32-edge half, nh: 64-col half
    const int lrow = lane & 15, quad = lane >> 4;
    f32x4 acc[2][4];
    #pragma unroll
    for (int i = 0; i < 2; ++i)
        #pragma unroll
        for (int j = 0; j < 4; ++j) { f32x4 z = {0.f, 0.f, 0.f, 0.f}; acc[i][j] = z; }
    const u16* Bp = W1s + lane * 8;
    for (int kc = 0; kc < 9; ++kc) {
        bf16x8 a[2], b[4];
        #pragma unroll
        for (int i = 0; i < 2; ++i)
            a[i] = *(const bf16x8*)(sa + (mh * 32 + i * 16 + lrow) * 296 + kc * 32 + quad * 8);
        #pragma unroll
        for (int j = 0; j < 4; ++j)
            b[j] = *(const bf16x8*)(Bp + (kc * 8 + nh * 4 + j) * 512);
        #pragma unroll
        for (int i = 0; i < 2; ++i)
            #pragma unroll
            for (int j = 0; j < 4; ++j)
                acc[i][j] = __builtin_amdgcn_mfma_f32_16x16x32_bf16(a[i], b[j], acc[i][j], 0, 0, 0);
    }
    __syncthreads();   // done reading A-tile; reuse LDS as ss
    float b1v[4];
    #pragma unroll
    for (int j = 0; j < 4; ++j) b1v[j] = b1[nh * 64 + j * 16 + lrow];
    #pragma unroll
    for (int i = 0; i < 2; ++i) {
        #pragma unroll
        for (int j = 0; j < 4; ++j) {
            int col = nh * 64 + j * 16 + lrow;
            #pragma unroll
            for (int r = 0; r < 4; ++r) {
                int row = mh * 32 + i * 16 + quad * 4 + r;
                float v = acc[i][j][r] + b1v[j];
                v = v / (1.0f + __expf(-v));
                ss[row * 132 + col] = v;
            }
        }
    }
    __syncthreads();
    {
        int col = tid & 127, r0 = (tid >> 7) * 32;
        float a = 0.f;
        for (int r = r0; r < r0 + 32; ++r) {
            a += ss[r * 132 + col];
            if (r == r0 + 31 || s_dst[r + 1] != s_dst[r]) {
                atomicAdd(&s_glob[(size_t)s_dst[r] * 128 + col], a);
                a = 0.f;
            }
        }
    }
}

// ---------------- node update: agg = s@W2 + deg*b2 ; h_up MLP ; residual+LN ----------------
__global__ __launch_bounds__(256) void k_node(const float* __restrict__ s_glob, const int* __restrict__ row_ptr,
        float* __restrict__ hf, u16* __restrict__ hb,
        const float* __restrict__ W2t, const float* __restrict__ V1t, const float* __restrict__ V2t,
        const float* __restrict__ b2, const float* __restrict__ c1, const float* __restrict__ c2,
        const float* __restrict__ lng, const float* __restrict__ lnb) {
    int j = threadIdx.x & 127, p = threadIdx.x >> 7;
    __shared__ alignas(16) float sv[2][128], hv[2][128], av[2][128], uv[2][128];
    __shared__ float red[2][2][2];
    for (int it = 0; it < 4; ++it) {
        int n = blockIdx.x * 8 + it * 2 + p;
        sv[p][j] = s_glob[(size_t)n * 128 + j];
        hv[p][j] = hf[(size_t)n * 128 + j];
        __syncthreads();
        int deg = row_ptr[n + 1] - row_ptr[n];
        float acc = (float)deg * b2[j];
        {
            const float4* wr = (const float4*)(W2t + j * 128);
            const float4* sp = (const float4*)sv[p];
            #pragma unroll 8
            for (int kk = 0; kk < 32; ++kk) {
                float4 w = wr[kk], s4 = sp[kk];
                acc += w.x * s4.x + w.y * s4.y + w.z * s4.z + w.w * s4.w;
            }
        }
        av[p][j] = acc;
        __syncthreads();
        float a1 = c1[j];
        {
            const float4* vr = (const float4*)(V1t + j * 256);
            const float4* hp = (const float4*)hv[p];
            const float4* ap = (const float4*)av[p];
            #pragma unroll 8
            for (int kk = 0; kk < 32; ++kk) {
                float4 w = vr[kk], h4 = hp[kk];
                a1 += w.x * h4.x + w.y * h4.y + w.z * h4.z + w.w * h4.w;
            }
            #pragma unroll 8
            for (int kk = 0; kk < 32; ++kk) {
                float4 w = vr[32 + kk], a4 = ap[kk];
                a1 += w.x * a4.x + w.y * a4.y + w.z * a4.z + w.w * a4.w;
            }
        }
        uv[p][j] = silu(a1);
        __syncthreads();
        float o = c2[j];
        {
            const float4* wr = (const float4*)(V2t + j * 128);
            const float4* up = (const float4*)uv[p];
            #pragma unroll 8
            for (int kk = 0; kk < 32; ++kk) {
                float4 w = wr[kk], u4 = up[kk];
                o += w.x * u4.x + w.y * u4.y + w.z * u4.z + w.w * u4.w;
            }
        }
        float xj = hv[p][j] + o;
        float s1 = xj, s2 = xj * xj;
        #pragma unroll
        for (int m = 1; m < 64; m <<= 1) {
            s1 += __shfl_xor(s1, m, 64);
            s2 += __shfl_xor(s2, m, 64);
        }
        int wip = j >> 6;
        if ((threadIdx.x & 63) == 0) { red[p][wip][0] = s1; red[p][wip][1] = s2; }
        __syncthreads();
        float S1 = red[p][0][0] + red[p][1][0];
        float S2 = red[p][0][1] + red[p][1][1];
        float mu = S1 * (1.0f / 128.0f);
        float var = S2 * (1.0f / 128.0f) - mu * mu;
        float y = (xj - mu) * rsqrtf(var + 1e-5f) * lng[j] + lnb[j];
        hf[(size_t)n * 128 + j] = y;
        hb[(size_t)n * 128 + j] = f2b(y);
        __syncthreads();
    }
}

// ---------------- output MLP (fp32 out) ----------------
__global__ __launch_bounds__(256) void k_out(const float* __restrict__ hf, const float* __restrict__ ow1t,
        const float* __restrict__ ob1, const float* __restrict__ ow2, const float* __restrict__ ob2,
        float* __restrict__ out) {
    int j = threadIdx.x & 127, p = threadIdx.x >> 7;
    __shared__ alignas(16) float hv[2][128], hid[2][128];
    for (int it = 0; it < 4; ++it) {
        int n = blockIdx.x * 8 + it * 2 + p;
        hv[p][j] = hf[(size_t)n * 128 + j];
        __syncthreads();
        float acc = ob1[j];
        const float4* wr = (const float4*)(ow1t + j * 128);
        const float4* hp = (const float4*)hv[p];
        #pragma unroll 8
        for (int kk = 0; kk < 32; ++kk) {
            float4 w = wr[kk], h4 = hp[kk];
            acc += w.x * h4.x + w.y * h4.y + w.z * h4.z + w.w * h4.w;
        }
        hid[p][j] = silu(acc);
        __syncthreads();
        if (j < 3) {
            float o = ob2[j];
            for (int k = 0; k < 128; ++k) o += hid[p][k] * ow2[k * 3 + j];
            out[(size_t)n * 3 + j] = o;
        }
        __syncthreads();
    }
}

extern "C" void kernel_launch(void* const* d_in, const int* in_sizes, int n_in,
                              void* d_out, int out_size, void* d_ws, size_t ws_size,
                              hipStream_t stream) {
    const float* x    = (const float*)d_in[0];
    const int* ei     = (const int*)d_in[1];
    const int* tptr   = (const int*)d_in[2];
    const float* tw1  = (const float*)d_in[3];
    const float* tb1  = (const float*)d_in[4];
    const float* tw2  = (const float*)d_in[5];
    const float* tb2  = (const float*)d_in[6];
    const float* nw1  = (const float*)d_in[7];
    const float* nb1  = (const float*)d_in[8];
    const float* nw2  = (const float*)d_in[9];
    const float* nb2  = (const float*)d_in[10];
    const float* pmw1 = (const float*)d_in[11];
    const float* pmb1 = (const float*)d_in[12];
    const float* pmw2 = (const float*)d_in[13];
    const float* pmb2 = (const float*)d_in[14];
    const float* phw1 = (const float*)d_in[15];
    const float* phb1 = (const float*)d_in[16];
    const float* phw2 = (const float*)d_in[17];
    const float* phb2 = (const float*)d_in[18];
    const float* lng  = (const float*)d_in[19];
    const float* lnb  = (const float*)d_in[20];
    const float* ow1  = (const float*)d_in[21];
    const float* ob1  = (const float*)d_in[22];
    const float* ow2  = (const float*)d_in[23];
    const float* ob2  = (const float*)d_in[24];
    float* out = (float*)d_out;

    char* wsp = (char*)d_ws;
    size_t off = 0;
    auto alloc = [&](size_t bytes) -> void* {
        void* p = wsp + off;
        off += (bytes + 255) & ~(size_t)255;
        return p;
    };
    int* hist    = (int*)alloc((size_t)NNODES * 4);
    int* cursor  = (int*)alloc((size_t)NNODES * 4);
    int* row_ptr = (int*)alloc((size_t)(NNODES + 1) * 4);
    int* ssrc    = (int*)alloc((size_t)NEDGES * 4);
    int* sdst    = (int*)alloc((size_t)NEDGES * 4);
    u16* W1s     = (u16*)alloc((size_t)3 * 9 * 8 * 512 * 2);
    float* base1 = (float*)alloc(128 * 4);
    float* W2t   = (float*)alloc((size_t)3 * 128 * 128 * 4);
    float* V1t   = (float*)alloc((size_t)3 * 128 * 256 * 4);
    float* V2t   = (float*)alloc((size_t)3 * 128 * 128 * 4);
    float* nw2t  = (float*)alloc((size_t)128 * 128 * 4);
    float* ow1t  = (float*)alloc((size_t)128 * 128 * 4);
    float* hf    = (float*)alloc((size_t)NNODES * 128 * 4);
    u16* hb      = (u16*)alloc((size_t)NNODES * 128 * 2);
    float* s_glob= (float*)alloc((size_t)NNODES * 128 * 4);

    (void)hipMemsetAsync(hist, 0, (size_t)NNODES * 4, stream);
    k_hist<<<NEDGES / 256, 256, 0, stream>>>(ei, hist);
    k_scan<<<1, 1024, 0, stream>>>(hist, row_ptr, cursor);
    k_scatter<<<NEDGES / 256, 256, 0, stream>>>(ei, cursor, ssrc, sdst);
    k_prep_w1s<<<54, 256, 0, stream>>>(pmw1, W1s);

    TMats tm;
    tm.s[0] = pmw2;          tm.d[0] = W2t;
    tm.s[1] = pmw2 + 16384;  tm.d[1] = W2t + 16384;
    tm.s[2] = pmw2 + 32768;  tm.d[2] = W2t + 32768;
    tm.s[3] = phw2;          tm.d[3] = V2t;
    tm.s[4] = phw2 + 16384;  tm.d[4] = V2t + 16384;
    tm.s[5] = phw2 + 32768;  tm.d[5] = V2t + 32768;
    tm.s[6] = nw2;           tm.d[6] = nw2t;
    tm.s[7] = ow1;           tm.d[7] = ow1t;
    k_transpose128<<<dim3(64, 8), 256, 0, stream>>>(tm);
    k_transpose_v1<<<dim3(128, 3), 256, 0, stream>>>(phw1, V1t);

    k_time<<<1, 128, 0, stream>>>(tptr, tw1, tb1, tw2, tb2, nw1, nb1, base1);
    k_h0<<<2500, 256, 0, stream>>>(x, base1, nw1, nw2t, nb2, hf, hb);

    for (int l = 0; l < 3; ++l) {
        (void)hipMemsetAsync(s_glob, 0, (size_t)NNODES * 128 * 4, stream);
        k_edge<<<NEDGES / 64, 256, 37888, stream>>>(hb, x, ssrc, sdst,
                W1s + (size_t)l * 36864, pmb1 + l * 128, s_glob);
        k_node<<<2500, 256, 0, stream>>>(s_glob, row_ptr, hf, hb,
                W2t + (size_t)l * 16384, V1t + (size_t)l * 32768, V2t + (size_t)l * 16384,
                pmb2 + l * 128, phb1 + l * 128, phb2 + l * 128, lng + l * 128, lnb + l * 128);
    }
    k_out<<<2500, 256, 0, stream>>>(hf, ow1t, ob1, ow2, ob2, out);
}

// Round 4
// 761.841 us; speedup vs baseline: 3.3158x; 3.3158x over previous
//
#include <hip/hip_runtime.h>

typedef unsigned short u16;
typedef unsigned int u32;

#define NNODES 20000
#define NEDGES 640000
// GAMMA = 1/(2*(sqrt(2)/15)^2) = 56.25 exactly
#define RBF_GAMMA 56.25f
#define SQRT2 1.4142135623730951f

typedef __bf16 bf16x8 __attribute__((ext_vector_type(8)));
typedef float f32x4 __attribute__((ext_vector_type(4)));

__device__ __forceinline__ float b2f(u16 u) {
    union { float f; u32 i; } x; x.i = ((u32)u) << 16; return x.f;
}
__device__ __forceinline__ u16 f2b(float f) {
    union { float f; u32 i; } x; x.f = f;
    u32 r = (x.i + 0x7fffu + ((x.i >> 16) & 1u)) >> 16;
    return (u16)r;
}
__device__ __forceinline__ float silu(float v) {
    return v / (1.0f + __expf(-v));
}
__device__ __forceinline__ float dot4(float4 a, float4 b) {
    return a.x * b.x + a.y * b.y + a.z * b.z + a.w * b.w;
}

// ---------------- sort by dst (counting sort) ----------------
__global__ __launch_bounds__(256) void k_hist(const int* __restrict__ ei, int* __restrict__ hist) {
    int e = blockIdx.x * 256 + threadIdx.x;
    atomicAdd(&hist[ei[NEDGES + e]], 1);
}

__global__ __launch_bounds__(1024) void k_scan(const int* __restrict__ hist,
                                               int* __restrict__ row_ptr,
                                               int* __restrict__ cursor) {
    __shared__ int psum[1024];
    int t = threadIdx.x;
    int base = t * 20;
    int s = 0;
    if (base < NNODES)
        for (int i = 0; i < 20; ++i) s += hist[base + i];
    psum[t] = s;
    __syncthreads();
    for (int off = 1; off < 1024; off <<= 1) {
        int v = (t >= off) ? psum[t - off] : 0;
        __syncthreads();
        psum[t] += v;
        __syncthreads();
    }
    int excl = psum[t] - s;
    if (base < NNODES) {
        int run = excl;
        for (int i = 0; i < 20; ++i) {
            row_ptr[base + i] = run;
            cursor[base + i] = run;
            run += hist[base + i];
        }
    }
    if (t == 1023) row_ptr[NNODES] = psum[1023];
}

__global__ __launch_bounds__(256) void k_scatter(const int* __restrict__ ei, int* __restrict__ cursor,
                                                 int* __restrict__ ssrc, int* __restrict__ sdst) {
    int e = blockIdx.x * 256 + threadIdx.x;
    int d = ei[NEDGES + e];
    int pos = atomicAdd(&cursor[d], 1);
    ssrc[pos] = ei[e];
    sdst[pos] = d;
}

// ---------------- W1 (fp32) -> bf16 frag-order shuffle ----------------
__global__ __launch_bounds__(256) void k_prep_w1s(const float* __restrict__ pmw1, u16* __restrict__ W1s) {
    int id = blockIdx.x * 256 + threadIdx.x;   // 13824 total
    int l = id / 4608; int r = id - l * 4608;
    int kc = r / 512;  int r2 = r - kc * 512;
    int nt = r2 >> 6;  int lane = r2 & 63;
    int kb = kc * 32 + (lane >> 4) * 8;
    int n = nt * 16 + (lane & 15);
    #pragma unroll
    for (int jj = 0; jj < 8; ++jj) {
        int k = kb + jj;
        W1s[id * 8 + jj] = (k < 272) ? f2b(pmw1[l * 34816 + k * 128 + n]) : (u16)0;
    }
}

// ---------------- pack fp32 [K][128] -> [K/4][128][4] for k-vectorized coalesced reads ----------------
struct PackM { const float* s[11]; float* d[11]; int K[11]; };
__global__ __launch_bounds__(256) void k_pack(PackM pm) {
    int m = blockIdx.y;
    int idx = blockIdx.x * 256 + threadIdx.x;
    if (idx >= pm.K[m] * 128) return;
    int k = idx >> 7, j = idx & 127;
    pm.d[m][(k >> 2) * 512 + j * 4 + (k & 3)] = pm.s[m][idx];
}

// ---------------- time embedding -> te -> base1 ----------------
__global__ __launch_bounds__(128) void k_time(const int* __restrict__ tptr,
        const float* __restrict__ tw1, const float* __restrict__ tb1,
        const float* __restrict__ tw2, const float* __restrict__ tb2,
        const float* __restrict__ nw1, const float* __restrict__ nb1,
        float* __restrict__ base1) {
    __shared__ float emb[128], hid[128], te[128];
    int j = threadIdx.x;
    int raw = tptr[0];
    float tv;
    if (raw >= 0 && raw < (1 << 24)) tv = (float)raw;
    else tv = __int_as_float(raw);
    float fr = expf(-9.210340371976184f * (float)(j & 63) / 63.0f);
    float a = tv * fr;
    emb[j] = (j < 64) ? sinf(a) : cosf(a);
    __syncthreads();
    float acc = tb1[j];
    for (int k = 0; k < 128; ++k) acc += emb[k] * tw1[k * 128 + j];
    hid[j] = silu(acc);
    __syncthreads();
    acc = tb2[j];
    for (int k = 0; k < 128; ++k) acc += hid[k] * tw2[k * 128 + j];
    te[j] = acc;
    __syncthreads();
    acc = nb1[j];
    for (int k = 0; k < 128; ++k) acc += te[k] * nw1[(3 + k) * 128 + j];
    base1[j] = acc;
}

// ---------------- input node MLP: 16 nodes/block, 2 cols x 4 nodes per thread ----------------
__global__ __launch_bounds__(256) void k_h0(const float* __restrict__ x, const float* __restrict__ base1,
        const float* __restrict__ nw1, const float* __restrict__ nw2p, const float* __restrict__ nb2,
        float* __restrict__ hf, u16* __restrict__ hb) {
    const int tid = threadIdx.x;
    const int c = tid & 63, g = tid >> 6;   // cols {2c,2c+1}, nodes g*4..g*4+3
    const int nb = g * 4;
    const int base = blockIdx.x * 16;
    __shared__ alignas(16) float xl[16][4];
    __shared__ alignas(16) float hid[16][128];
    if (tid < 48) { int n = tid / 3, cc = tid - n * 3; xl[n][cc] = x[(size_t)(base + n) * 3 + cc]; }
    __syncthreads();
    int j0 = 2 * c, j1 = 2 * c + 1;
    float w0a = nw1[j0], w0b = nw1[j1];
    float w1a = nw1[128 + j0], w1b = nw1[128 + j1];
    float w2a = nw1[256 + j0], w2b = nw1[256 + j1];
    float ba = base1[j0], bb = base1[j1];
    #pragma unroll
    for (int n = 0; n < 4; ++n) {
        float x0 = xl[nb + n][0], x1 = xl[nb + n][1], x2 = xl[nb + n][2];
        float2 v;
        v.x = silu(ba + x0 * w0a + x1 * w1a + x2 * w2a);
        v.y = silu(bb + x0 * w0b + x1 * w1b + x2 * w2b);
        *(float2*)&hid[nb + n][j0] = v;
    }
    __syncthreads();
    float acc[4][2];
    {
        float za = nb2[j0], zb = nb2[j1];
        #pragma unroll
        for (int n = 0; n < 4; ++n) { acc[n][0] = za; acc[n][1] = zb; }
    }
    for (int kk = 0; kk < 32; ++kk) {
        float4 wa = *(const float4*)(nw2p + kk * 512 + j0 * 4);
        float4 wb = *(const float4*)(nw2p + kk * 512 + j1 * 4);
        #pragma unroll
        for (int n = 0; n < 4; ++n) {
            float4 s4 = *(const float4*)&hid[nb + n][kk * 4];
            acc[n][0] += dot4(wa, s4);
            acc[n][1] += dot4(wb, s4);
        }
    }
    #pragma unroll
    for (int n = 0; n < 4; ++n) {
        int node = base + nb + n;
        *(float2*)&hf[(size_t)node * 128 + j0] = make_float2(acc[n][0], acc[n][1]);
        u32 pk = (u32)f2b(acc[n][0]) | ((u32)f2b(acc[n][1]) << 16);
        *(u32*)&hb[(size_t)node * 128 + j0] = pk;
    }
}

// ---------------- edge message GEMM + silu + segment reduce (unchanged) ----------------
__global__ __launch_bounds__(256) void k_edge(
        const u16* __restrict__ hb, const float* __restrict__ x,
        const int* __restrict__ ssrc, const int* __restrict__ sdst,
        const u16* __restrict__ W1s, const float* __restrict__ b1,
        float* __restrict__ s_glob) {
    extern __shared__ char dynsm[];
    u16* sa = (u16*)dynsm;          // [64][296] bf16
    float* ss = (float*)dynsm;      // reused: [64][132] f32
    __shared__ int s_src[64], s_dst[64];
    const int tid = threadIdx.x;
    const int e0 = blockIdx.x * 64;
    if (tid < 64) { s_src[tid] = ssrc[e0 + tid]; s_dst[tid] = sdst[e0 + tid]; }
    __syncthreads();
    #pragma unroll
    for (int c = tid; c < 2048; c += 256) {
        int e = c >> 5, part = c & 31;
        int node = (part < 16) ? s_src[e] : s_dst[e];
        uint4 v = *(const uint4*)(hb + (size_t)node * 128 + (part & 15) * 8);
        *(uint4*)(sa + e * 296 + part * 8) = v;
    }
    for (int c = tid; c < 320; c += 256) {
        int e = c / 5, p = c - e * 5;
        if (p < 2) {
            int s = s_src[e], d = s_dst[e];
            float ddx = x[(size_t)s * 3] - x[(size_t)d * 3];
            float ddy = x[(size_t)s * 3 + 1] - x[(size_t)d * 3 + 1];
            float r = sqrtf(ddx * ddx + ddy * ddy + 1e-8f);
            alignas(16) u16 tmp[8];
            #pragma unroll
            for (int jj = 0; jj < 8; ++jj) {
                int j = p * 8 + jj;
                float cen = SQRT2 * (float)j / 15.0f;
                float dd = r - cen;
                tmp[jj] = f2b(__expf(-RBF_GAMMA * dd * dd));
            }
            *(uint4*)(sa + e * 296 + 256 + p * 8) = *(const uint4*)tmp;
        } else {
            *(uint4*)(sa + e * 296 + 256 + p * 8) = make_uint4(0, 0, 0, 0);
        }
    }
    __syncthreads();

    const int lane = tid & 63, w = tid >> 6;
    const int mh = w >> 1, nh = w & 1;
    const int lrow = lane & 15, quad = lane >> 4;
    f32x4 acc[2][4];
    #pragma unroll
    for (int i = 0; i < 2; ++i)
        #pragma unroll
        for (int j = 0; j < 4; ++j) { f32x4 z = {0.f, 0.f, 0.f, 0.f}; acc[i][j] = z; }
    const u16* Bp = W1s + lane * 8;
    for (int kc = 0; kc < 9; ++kc) {
        bf16x8 a[2], b[4];
        #pragma unroll
        for (int i = 0; i < 2; ++i)
            a[i] = *(const bf16x8*)(sa + (mh * 32 + i * 16 + lrow) * 296 + kc * 32 + quad * 8);
        #pragma unroll
        for (int j = 0; j < 4; ++j)
            b[j] = *(const bf16x8*)(Bp + (kc * 8 + nh * 4 + j) * 512);
        #pragma unroll
        for (int i = 0; i < 2; ++i)
            #pragma unroll
            for (int j = 0; j < 4; ++j)
                acc[i][j] = __builtin_amdgcn_mfma_f32_16x16x32_bf16(a[i], b[j], acc[i][j], 0, 0, 0);
    }
    __syncthreads();
    float b1v[4];
    #pragma unroll
    for (int j = 0; j < 4; ++j) b1v[j] = b1[nh * 64 + j * 16 + lrow];
    #pragma unroll
    for (int i = 0; i < 2; ++i) {
        #pragma unroll
        for (int j = 0; j < 4; ++j) {
            int col = nh * 64 + j * 16 + lrow;
            #pragma unroll
            for (int r = 0; r < 4; ++r) {
                int row = mh * 32 + i * 16 + quad * 4 + r;
                float v = acc[i][j][r] + b1v[j];
                v = v / (1.0f + __expf(-v));
                ss[row * 132 + col] = v;
            }
        }
    }
    __syncthreads();
    {
        int col = tid & 127, r0 = (tid >> 7) * 32;
        float a = 0.f;
        for (int r = r0; r < r0 + 32; ++r) {
            a += ss[r * 132 + col];
            if (r == r0 + 31 || s_dst[r + 1] != s_dst[r]) {
                atomicAdd(&s_glob[(size_t)s_dst[r] * 128 + col], a);
                a = 0.f;
            }
        }
    }
}

// ---------------- node update: coalesced packed weights, 16 nodes/block ----------------
__global__ __launch_bounds__(256) void k_node(const float* __restrict__ s_glob, const int* __restrict__ row_ptr,
        float* __restrict__ hf, u16* __restrict__ hb,
        const float* __restrict__ W2p, const float* __restrict__ V1p, const float* __restrict__ V2p,
        const float* __restrict__ b2, const float* __restrict__ c1, const float* __restrict__ c2,
        const float* __restrict__ lng, const float* __restrict__ lnb) {
    const int tid = threadIdx.x;
    const int c = tid & 63, g = tid >> 6;   // cols {2c,2c+1}, nodes g*4..g*4+3
    const int nb = g * 4;
    const int j0 = 2 * c, j1 = 2 * c + 1;
    const int base = blockIdx.x * 16;
    __shared__ alignas(16) float sv[16][128], hv[16][128], av[16][128], uv[16][128];
    __shared__ float mv[16][2];
    float (*xs)[128] = sv;   // sv dead after GEMM1; reuse for LN input

    const float4* sg4 = (const float4*)(s_glob + (size_t)base * 128);
    const float4* hg4 = (const float4*)(hf + (size_t)base * 128);
    for (int q = tid; q < 512; q += 256) {
        ((float4*)sv)[q] = sg4[q];
        ((float4*)hv)[q] = hg4[q];
    }
    __syncthreads();

    float acc[4][2];
    // ---- GEMM1: av = sv @ W2 + deg*b2 ----
    {
        float ba = b2[j0], bb = b2[j1];
        #pragma unroll
        for (int n = 0; n < 4; ++n) {
            int node = base + nb + n;
            float dg = (float)(row_ptr[node + 1] - row_ptr[node]);
            acc[n][0] = dg * ba; acc[n][1] = dg * bb;
        }
        for (int kk = 0; kk < 32; ++kk) {
            float4 wa = *(const float4*)(W2p + kk * 512 + j0 * 4);
            float4 wb = *(const float4*)(W2p + kk * 512 + j1 * 4);
            #pragma unroll
            for (int n = 0; n < 4; ++n) {
                float4 s4 = *(const float4*)&sv[nb + n][kk * 4];
                acc[n][0] += dot4(wa, s4);
                acc[n][1] += dot4(wb, s4);
            }
        }
        #pragma unroll
        for (int n = 0; n < 4; ++n)
            *(float2*)&av[nb + n][j0] = make_float2(acc[n][0], acc[n][1]);
    }
    __syncthreads();
    // ---- GEMM2: uv = silu([hv|av] @ V1 + c1) ----
    {
        float ba = c1[j0], bb = c1[j1];
        #pragma unroll
        for (int n = 0; n < 4; ++n) { acc[n][0] = ba; acc[n][1] = bb; }
        for (int kk = 0; kk < 32; ++kk) {
            float4 wa = *(const float4*)(V1p + kk * 512 + j0 * 4);
            float4 wb = *(const float4*)(V1p + kk * 512 + j1 * 4);
            #pragma unroll
            for (int n = 0; n < 4; ++n) {
                float4 s4 = *(const float4*)&hv[nb + n][kk * 4];
                acc[n][0] += dot4(wa, s4);
                acc[n][1] += dot4(wb, s4);
            }
        }
        for (int kk = 32; kk < 64; ++kk) {
            float4 wa = *(const float4*)(V1p + kk * 512 + j0 * 4);
            float4 wb = *(const float4*)(V1p + kk * 512 + j1 * 4);
            #pragma unroll
            for (int n = 0; n < 4; ++n) {
                float4 s4 = *(const float4*)&av[nb + n][(kk - 32) * 4];
                acc[n][0] += dot4(wa, s4);
                acc[n][1] += dot4(wb, s4);
            }
        }
        #pragma unroll
        for (int n = 0; n < 4; ++n)
            *(float2*)&uv[nb + n][j0] = make_float2(silu(acc[n][0]), silu(acc[n][1]));
    }
    __syncthreads();
    // ---- GEMM3: o = uv @ V2 + c2 ; xj = hv + o ----
    {
        float ba = c2[j0], bb = c2[j1];
        #pragma unroll
        for (int n = 0; n < 4; ++n) { acc[n][0] = ba; acc[n][1] = bb; }
        for (int kk = 0; kk < 32; ++kk) {
            float4 wa = *(const float4*)(V2p + kk * 512 + j0 * 4);
            float4 wb = *(const float4*)(V2p + kk * 512 + j1 * 4);
            #pragma unroll
            for (int n = 0; n < 4; ++n) {
                float4 s4 = *(const float4*)&uv[nb + n][kk * 4];
                acc[n][0] += dot4(wa, s4);
                acc[n][1] += dot4(wb, s4);
            }
        }
        #pragma unroll
        for (int n = 0; n < 4; ++n) {
            float2 h2 = *(const float2*)&hv[nb + n][j0];
            acc[n][0] += h2.x; acc[n][1] += h2.y;
        }
    }
    __syncthreads();   // everyone done reading sv(GEMM1 done long ago) before xs overwrite
    #pragma unroll
    for (int n = 0; n < 4; ++n)
        *(float2*)&xs[nb + n][j0] = make_float2(acc[n][0], acc[n][1]);
    __syncthreads();
    // ---- LN ----
    {
        int row = tid >> 4, part = tid & 15;
        float4 a = *(const float4*)&xs[row][part * 8];
        float4 b = *(const float4*)&xs[row][part * 8 + 4];
        float s1 = a.x + a.y + a.z + a.w + b.x + b.y + b.z + b.w;
        float s2 = a.x * a.x + a.y * a.y + a.z * a.z + a.w * a.w
                 + b.x * b.x + b.y * b.y + b.z * b.z + b.w * b.w;
        #pragma unroll
        for (int m = 1; m < 16; m <<= 1) {
            s1 += __shfl_xor(s1, m, 64);
            s2 += __shfl_xor(s2, m, 64);
        }
        if (part == 0) { mv[row][0] = s1; mv[row][1] = s2; }
    }
    __syncthreads();
    {
        float ga = lng[j0], gb = lng[j1];
        float bba = lnb[j0], bbb = lnb[j1];
        #pragma unroll
        for (int n = 0; n < 4; ++n) {
            int row = nb + n;
            float mu = mv[row][0] * (1.0f / 128.0f);
            float var = mv[row][1] * (1.0f / 128.0f) - mu * mu;
            float rs = rsqrtf(var + 1e-5f);
            float y0 = (xs[row][j0] - mu) * rs * ga + bba;
            float y1 = (xs[row][j1] - mu) * rs * gb + bbb;
            int node = base + row;
            *(float2*)&hf[(size_t)node * 128 + j0] = make_float2(y0, y1);
            u32 pk = (u32)f2b(y0) | ((u32)f2b(y1) << 16);
            *(u32*)&hb[(size_t)node * 128 + j0] = pk;
        }
    }
}

// ---------------- output MLP (fp32 out) ----------------
__global__ __launch_bounds__(256) void k_out(const float* __restrict__ hf, const float* __restrict__ ow1p,
        const float* __restrict__ ob1, const float* __restrict__ ow2, const float* __restrict__ ob2,
        float* __restrict__ out) {
    const int tid = threadIdx.x;
    const int c = tid & 63, g = tid >> 6;
    const int nb = g * 4;
    const int j0 = 2 * c, j1 = 2 * c + 1;
    const int base = blockIdx.x * 16;
    __shared__ alignas(16) float hv[16][128];
    __shared__ float hid[16][132];
    const float4* hg4 = (const float4*)(hf + (size_t)base * 128);
    for (int q = tid; q < 512; q += 256) ((float4*)hv)[q] = hg4[q];
    __syncthreads();
    float acc[4][2];
    {
        float ba = ob1[j0], bb = ob1[j1];
        #pragma unroll
        for (int n = 0; n < 4; ++n) { acc[n][0] = ba; acc[n][1] = bb; }
    }
    for (int kk = 0; kk < 32; ++kk) {
        float4 wa = *(const float4*)(ow1p + kk * 512 + j0 * 4);
        float4 wb = *(const float4*)(ow1p + kk * 512 + j1 * 4);
        #pragma unroll
        for (int n = 0; n < 4; ++n) {
            float4 s4 = *(const float4*)&hv[nb + n][kk * 4];
            acc[n][0] += dot4(wa, s4);
            acc[n][1] += dot4(wb, s4);
        }
    }
    #pragma unroll
    for (int n = 0; n < 4; ++n) {
        hid[nb + n][j0] = silu(acc[n][0]);
        hid[nb + n][j1] = silu(acc[n][1]);
    }
    __syncthreads();
    if (tid < 48) {
        int n = tid / 3, cc = tid - n * 3;
        float o = ob2[cc];
        for (int k = 0; k < 128; ++k) o += hid[n][k] * ow2[k * 3 + cc];
        out[(size_t)(base + n) * 3 + cc] = o;
    }
}

extern "C" void kernel_launch(void* const* d_in, const int* in_sizes, int n_in,
                              void* d_out, int out_size, void* d_ws, size_t ws_size,
                              hipStream_t stream) {
    const float* x    = (const float*)d_in[0];
    const int* ei     = (const int*)d_in[1];
    const int* tptr   = (const int*)d_in[2];
    const float* tw1  = (const float*)d_in[3];
    const float* tb1  = (const float*)d_in[4];
    const float* tw2  = (const float*)d_in[5];
    const float* tb2  = (const float*)d_in[6];
    const float* nw1  = (const float*)d_in[7];
    const float* nb1  = (const float*)d_in[8];
    const float* nw2  = (const float*)d_in[9];
    const float* nb2  = (const float*)d_in[10];
    const float* pmw1 = (const float*)d_in[11];
    const float* pmb1 = (const float*)d_in[12];
    const float* pmw2 = (const float*)d_in[13];
    const float* pmb2 = (const float*)d_in[14];
    const float* phw1 = (const float*)d_in[15];
    const float* phb1 = (const float*)d_in[16];
    const float* phw2 = (const float*)d_in[17];
    const float* phb2 = (const float*)d_in[18];
    const float* lng  = (const float*)d_in[19];
    const float* lnb  = (const float*)d_in[20];
    const float* ow1  = (const float*)d_in[21];
    const float* ob1  = (const float*)d_in[22];
    const float* ow2  = (const float*)d_in[23];
    const float* ob2  = (const float*)d_in[24];
    float* out = (float*)d_out;

    char* wsp = (char*)d_ws;
    size_t off = 0;
    auto alloc = [&](size_t bytes) -> void* {
        void* p = wsp + off;
        off += (bytes + 255) & ~(size_t)255;
        return p;
    };
    int* hist    = (int*)alloc((size_t)NNODES * 4);
    int* cursor  = (int*)alloc((size_t)NNODES * 4);
    int* row_ptr = (int*)alloc((size_t)(NNODES + 1) * 4);
    int* ssrc    = (int*)alloc((size_t)NEDGES * 4);
    int* sdst    = (int*)alloc((size_t)NEDGES * 4);
    u16* W1s     = (u16*)alloc((size_t)3 * 9 * 8 * 512 * 2);
    float* base1 = (float*)alloc(128 * 4);
    float* W2p   = (float*)alloc((size_t)3 * 128 * 128 * 4);
    float* V1p   = (float*)alloc((size_t)3 * 256 * 128 * 4);
    float* V2p   = (float*)alloc((size_t)3 * 128 * 128 * 4);
    float* nw2p  = (float*)alloc((size_t)128 * 128 * 4);
    float* ow1p  = (float*)alloc((size_t)128 * 128 * 4);
    float* hf    = (float*)alloc((size_t)NNODES * 128 * 4);
    u16* hb      = (u16*)alloc((size_t)NNODES * 128 * 2);
    float* s_glob= (float*)alloc((size_t)NNODES * 128 * 4);

    (void)hipMemsetAsync(hist, 0, (size_t)NNODES * 4, stream);
    k_hist<<<NEDGES / 256, 256, 0, stream>>>(ei, hist);
    k_scan<<<1, 1024, 0, stream>>>(hist, row_ptr, cursor);
    k_scatter<<<NEDGES / 256, 256, 0, stream>>>(ei, cursor, ssrc, sdst);
    k_prep_w1s<<<54, 256, 0, stream>>>(pmw1, W1s);

    PackM pm;
    for (int l = 0; l < 3; ++l) {
        pm.s[l] = pmw2 + (size_t)l * 16384;  pm.d[l] = W2p + (size_t)l * 16384;  pm.K[l] = 128;
        pm.s[3 + l] = phw2 + (size_t)l * 16384; pm.d[3 + l] = V2p + (size_t)l * 16384; pm.K[3 + l] = 128;
        pm.s[6 + l] = phw1 + (size_t)l * 32768; pm.d[6 + l] = V1p + (size_t)l * 32768; pm.K[6 + l] = 256;
    }
    pm.s[9] = nw2;  pm.d[9] = nw2p;  pm.K[9] = 128;
    pm.s[10] = ow1; pm.d[10] = ow1p; pm.K[10] = 128;
    k_pack<<<dim3(128, 11), 256, 0, stream>>>(pm);

    k_time<<<1, 128, 0, stream>>>(tptr, tw1, tb1, tw2, tb2, nw1, nb1, base1);
    k_h0<<<1250, 256, 0, stream>>>(x, base1, nw1, nw2p, nb2, hf, hb);

    for (int l = 0; l < 3; ++l) {
        (void)hipMemsetAsync(s_glob, 0, (size_t)NNODES * 128 * 4, stream);
        k_edge<<<NEDGES / 64, 256, 37888, stream>>>(hb, x, ssrc, sdst,
                W1s + (size_t)l * 36864, pmb1 + l * 128, s_glob);
        k_node<<<1250, 256, 0, stream>>>(s_glob, row_ptr, hf, hb,
                W2p + (size_t)l * 16384, V1p + (size_t)l * 32768, V2p + (size_t)l * 16384,
                pmb2 + l * 128, phb1 + l * 128, phb2 + l * 128, lng + l * 128, lnb + l * 128);
    }
    k_out<<<1250, 256, 0, stream>>>(hf, ow1p, ob1, ow2, ob2, out);
}